// Round 3
// baseline (328.384 us; speedup 1.0000x reference)
//
#include <hip/hip_runtime.h>
#include <math.h>

#define PW 256
#define PH 256
#define IW 4096
#define IH 2048
#define NB 64
#define PI_F 3.14159265358979323846f

// One block = one output row (b, y); 256 threads = 256 x-positions.
// Per-batch rotation matrix + focal computed by thread 0 into LDS (no d_ws).
__global__ __launch_bounds__(256) void e2p_kernel(
    const float* __restrict__ img,      // (3, IH, IW)
    const float* __restrict__ fov,      // (1,)
    const float* __restrict__ roll,     // (1,)
    const float* __restrict__ pitch,    // (1,)
    const float* __restrict__ yaw,      // (NB,)
    float* __restrict__ out)            // (NB, 3, PH, PW)
{
    const int x = threadIdx.x;
    const int row = blockIdx.x;
    const int y = row & (PH - 1);
    const int b = row >> 8;

    __shared__ float P[10];   // r00..r22, f
    if (threadIdx.x == 0) {
        float sr, cr, sp, cp, sy, cy;
        sincosf(roll[0], &sr, &cr);
        sincosf(pitch[0], &sp, &cp);
        sincosf(yaw[b], &sy, &cy);
        const float fovr = fov[0] * 0.017453292519943295f;   // deg2rad
        // R = Rz(yaw) @ Ry(pitch) @ Rx(roll)
        P[0] = cy * cp; P[1] = cy * sp * sr - sy * cr; P[2] = cy * sp * cr + sy * sr;
        P[3] = sy * cp; P[4] = sy * sp * sr + cy * cr; P[5] = sy * sp * cr - cy * sr;
        P[6] = -sp;     P[7] = cp * sr;                P[8] = cp * cr;
        P[9] = (float)PW / (2.0f * tanf(fovr * 0.5f));
    }
    __syncthreads();

    const float r00 = P[0], r01 = P[1], r02 = P[2];
    const float r10 = P[3], r11 = P[4], r12 = P[5];
    const float r20 = P[6], r21 = P[7], r22 = P[8];
    const float f   = P[9];

    const float dx = ((float)x - 128.0f) / f;   // cx = PW/2
    const float dy = ((float)y - 128.0f) / f;   // cy = PH/2

    const float d0 = r00 * dx + r01 * dy + r02;
    const float d1 = r10 * dx + r11 * dy + r12;
    const float d2 = r20 * dx + r21 * dy + r22;

    const float nrm = sqrtf(d0 * d0 + d1 * d1 + d2 * d2);
    const float phi = asinf(d2 / nrm);
    const float theta = atan2f(d1, d0);

    float ui = fmodf((theta - PI_F) * (float)IW / (2.0f * PI_F) + 0.5f, (float)IW);
    if (ui < 0.0f) ui += (float)IW;
    float uj = fmodf((phi - 0.5f * PI_F) * (float)IH / PI_F + 0.5f, (float)IH);
    if (uj < 0.0f) uj += (float)IH;

    const float u0f = floorf(ui);
    const float v0f = floorf(uj);
    const float du = ui - u0f;
    const float dv = uj - v0f;

    int u0 = ((int)u0f) & (IW - 1);     // ui >= 0 guaranteed; handles ui==IW edge too
    int u1 = (u0 + 1) & (IW - 1);
    int v0 = (int)v0f;
    if (v0 < 0) v0 = 0;
    if (v0 > IH - 1) v0 = IH - 1;
    int v1 = v0 + 1;
    if (v1 > IH - 1) v1 = IH - 1;

    const float w00 = (1.0f - du) * (1.0f - dv);
    const float w01 = du * (1.0f - dv);
    const float w10 = (1.0f - du) * dv;
    const float w11 = du * dv;

    const int i00 = v0 * IW + u0;
    const int i01 = v0 * IW + u1;
    const int i10 = v1 * IW + u0;
    const int i11 = v1 * IW + u1;

    float* o = out + ((size_t)(b * 3) * PH + y) * PW + x;
#pragma unroll
    for (int c = 0; c < 3; ++c) {
        const float* ic = img + (size_t)c * (IH * IW);
        float v = ic[i00] * w00 + ic[i01] * w01 + ic[i10] * w10 + ic[i11] * w11;
        o[(size_t)c * PH * PW] = tanhf(v);
    }
}

extern "C" void kernel_launch(void* const* d_in, const int* in_sizes, int n_in,
                              void* d_out, int out_size, void* d_ws, size_t ws_size,
                              hipStream_t stream) {
    const float* img   = (const float*)d_in[0];
    const float* fov   = (const float*)d_in[1];
    const float* roll  = (const float*)d_in[2];
    const float* pitch = (const float*)d_in[3];
    const float* yaw   = (const float*)d_in[4];
    float* out = (float*)d_out;

    e2p_kernel<<<NB * PH, 256, 0, stream>>>(img, fov, roll, pitch, yaw, out);
}

// Round 4
// 112.514 us; speedup vs baseline: 2.9186x; 2.9186x over previous
//
#include <hip/hip_runtime.h>
#include <math.h>

#define PW 256
#define PH 256
#define IW 4096
#define IH 2048
#define NB 64
#define PI_F 3.14159265358979323846f

// Block = 16x16 output tile. Grid decode pins all 64 batches of one tile
// location onto the same (heuristic, bid%8) XCD so their shared v-band
// (phi is yaw-independent!) is fetched once into that XCD's L2.
__global__ __launch_bounds__(256) void e2p_kernel(
    const float* __restrict__ img,      // (3, IH, IW)
    const float* __restrict__ fov,      // (1,)
    const float* __restrict__ roll,     // (1,)
    const float* __restrict__ pitch,    // (1,)
    const float* __restrict__ yaw,      // (NB,)
    float* __restrict__ out)            // (NB, 3, PH, PW)
{
    // ---- grid decode: g -> (xcd, batch, tile) ----
    const int g    = blockIdx.x;        // 0..16383
    const int x8   = g & 7;             // heuristic XCD (dispatch round-robin)
    const int q    = g >> 3;            // 0..2047
    const int b    = q & 63;            // batch innermost -> 64 batches of a
    const int tsub = q >> 6;            // tile co-resident on one XCD
    const int tile = tsub * 8 + x8;     // 0..255 (bijective)
    const int tx   = tile & 15;
    const int ty   = tile >> 4;
    const int lx   = threadIdx.x & 15;
    const int ly   = threadIdx.x >> 4;
    const int x    = tx * 16 + lx;
    const int y    = ty * 16 + ly;

    __shared__ float P[10];   // r00..r22, f
    if (threadIdx.x == 0) {
        float sr, cr, sp, cp, sy, cy;
        sincosf(roll[0], &sr, &cr);
        sincosf(pitch[0], &sp, &cp);
        sincosf(yaw[b], &sy, &cy);
        const float fovr = fov[0] * 0.017453292519943295f;   // deg2rad
        // R = Rz(yaw) @ Ry(pitch) @ Rx(roll)
        P[0] = cy * cp; P[1] = cy * sp * sr - sy * cr; P[2] = cy * sp * cr + sy * sr;
        P[3] = sy * cp; P[4] = sy * sp * sr + cy * cr; P[5] = sy * sp * cr - cy * sr;
        P[6] = -sp;     P[7] = cp * sr;                P[8] = cp * cr;
        P[9] = (float)PW / (2.0f * tanf(fovr * 0.5f));
    }
    __syncthreads();

    const float r00 = P[0], r01 = P[1], r02 = P[2];
    const float r10 = P[3], r11 = P[4], r12 = P[5];
    const float r20 = P[6], r21 = P[7], r22 = P[8];
    const float f   = P[9];

    const float dx = ((float)x - 128.0f) / f;   // cx = PW/2
    const float dy = ((float)y - 128.0f) / f;   // cy = PH/2

    const float d0 = r00 * dx + r01 * dy + r02;
    const float d1 = r10 * dx + r11 * dy + r12;
    const float d2 = r20 * dx + r21 * dy + r22;

    const float nrm = sqrtf(d0 * d0 + d1 * d1 + d2 * d2);
    const float phi = asinf(d2 / nrm);
    const float theta = atan2f(d1, d0);

    float ui = fmodf((theta - PI_F) * (float)IW / (2.0f * PI_F) + 0.5f, (float)IW);
    if (ui < 0.0f) ui += (float)IW;
    float uj = fmodf((phi - 0.5f * PI_F) * (float)IH / PI_F + 0.5f, (float)IH);
    if (uj < 0.0f) uj += (float)IH;

    const float u0f = floorf(ui);
    const float v0f = floorf(uj);
    const float du = ui - u0f;
    const float dv = uj - v0f;

    int u0 = ((int)u0f) & (IW - 1);     // ui >= 0 guaranteed; handles ui==IW edge too
    int u1 = (u0 + 1) & (IW - 1);
    int v0 = (int)v0f;
    if (v0 < 0) v0 = 0;
    if (v0 > IH - 1) v0 = IH - 1;
    int v1 = v0 + 1;
    if (v1 > IH - 1) v1 = IH - 1;

    const float w00 = (1.0f - du) * (1.0f - dv);
    const float w01 = du * (1.0f - dv);
    const float w10 = (1.0f - du) * dv;
    const float w11 = du * dv;

    const int i00 = v0 * IW + u0;
    const int i01 = v0 * IW + u1;
    const int i10 = v1 * IW + u0;
    const int i11 = v1 * IW + u1;

    float* o = out + ((size_t)(b * 3) * PH + y) * PW + x;
#pragma unroll
    for (int c = 0; c < 3; ++c) {
        const float* ic = img + (size_t)c * (IH * IW);
        float v = ic[i00] * w00 + ic[i01] * w01 + ic[i10] * w10 + ic[i11] * w11;
        o[(size_t)c * PH * PW] = tanhf(v);
    }
}

extern "C" void kernel_launch(void* const* d_in, const int* in_sizes, int n_in,
                              void* d_out, int out_size, void* d_ws, size_t ws_size,
                              hipStream_t stream) {
    const float* img   = (const float*)d_in[0];
    const float* fov   = (const float*)d_in[1];
    const float* roll  = (const float*)d_in[2];
    const float* pitch = (const float*)d_in[3];
    const float* yaw   = (const float*)d_in[4];
    float* out = (float*)d_out;

    e2p_kernel<<<NB * PH, 256, 0, stream>>>(img, fov, roll, pitch, yaw, out);
}